// Round 6
// baseline (548.412 us; speedup 1.0000x reference)
//
#include <hip/hip_runtime.h>

// imgs (8,3,1024,1024) fp32, z (1e6,2) fp32 -> out (8,2) fp32.
// R6 reformulation: the op is LINEAR in imgs. Each point deposits 4 bilinear
// coefficient weights into two weight images W0,W1 (point-independent of b,c);
// then out[b][j] = sum_p (sum_c imgs[b,c,p]) * Wj[p]. This replaces the whole
// sort+gather pipeline (R5: 334 us, ~210 us of it in hist/scan/scatter) with
// one atomic scatter into 8 MB + one coalesced streaming dot product.
//
// Coefficient derivation (u = x0x - xg, v = x0y - yg, both in [0,1)):
//   gc0: g00*(u-1), g01*(-u),  g10*(1-u), g11*(u)
//   gc1: g00*(v-1), g01*(1-v), g10*(-v),  g11*(v)
// (g10 = row yg+1; row stride NYX. Verified against reference algebra.)

#define NYX 1024
#define NPIX (NYX * NYX)
#define NB4 (NPIX / 4)          // 262144 float4 pixel-groups per plane
#define BATCH 8
#define CH 3

// ws layout: float2 W[NPIX] at offset 0 (8 MB), interleaved (w0,w1) per pixel.

__global__ __launch_bounds__(256) void zero_w_kernel(
    float4* __restrict__ W4, float* __restrict__ out)
{
    int t = blockIdx.x * blockDim.x + threadIdx.x;
    if (t < NPIX / 2) W4[t] = make_float4(0.0f, 0.0f, 0.0f, 0.0f);
    if (t < 16) out[t] = 0.0f;
}

__global__ __launch_bounds__(256) void scatter_w_kernel(
    const float* __restrict__ z, float2* __restrict__ W, int npts)
{
    int p = blockIdx.x * blockDim.x + threadIdx.x;
    if (p >= npts) return;
    float2 zz = ((const float2*)z)[p];
    float x0y = zz.x * (float)(NYX - 1);
    float x0x = zz.y * (float)(NYX - 1);
    bool oob = (x0y < 0.0f) || (x0y > (float)(NYX - 1)) ||
               (x0x < 0.0f) || (x0x > (float)(NYX - 1));
    if (oob) return;
    int yg = min((int)floorf(x0y), NYX - 2);
    int xg = min((int)floorf(x0x), NYX - 2);
    float u = x0x - (float)xg;   // [0,1)
    float v = x0y - (float)yg;

    float* w = (float*)(W + (size_t)yg * NYX + xg);
    // (yg, xg)
    unsafeAtomicAdd(w + 0, u - 1.0f);
    unsafeAtomicAdd(w + 1, v - 1.0f);
    // (yg, xg+1)
    unsafeAtomicAdd(w + 2, -u);
    unsafeAtomicAdd(w + 3, 1.0f - v);
    // (yg+1, xg)
    unsafeAtomicAdd(w + 2 * NYX + 0, 1.0f - u);
    unsafeAtomicAdd(w + 2 * NYX + 1, -v);
    // (yg+1, xg+1)
    unsafeAtomicAdd(w + 2 * NYX + 2, u);
    unsafeAtomicAdd(w + 2 * NYX + 3, v);
}

__global__ __launch_bounds__(256) void dot_kernel(
    const float4* __restrict__ imgs4, const float4* __restrict__ W4,
    float* __restrict__ out)
{
    float acc0[BATCH];
    float acc1[BATCH];
#pragma unroll
    for (int b = 0; b < BATCH; ++b) { acc0[b] = 0.0f; acc1[b] = 0.0f; }

    int stride = gridDim.x * blockDim.x;
    for (int t = blockIdx.x * blockDim.x + threadIdx.x; t < NB4; t += stride) {
        // wa: pixels 4t,4t+1 -> (W0,W1,W0,W1); wb: pixels 4t+2,4t+3
        float4 wa = W4[2 * t + 0];
        float4 wb = W4[2 * t + 1];
#pragma unroll
        for (int b = 0; b < BATCH; ++b) {
            const float4* pb = imgs4 + (size_t)(b * CH) * NB4 + t;
            float4 s0 = pb[0];
            float4 s1 = pb[NB4];
            float4 s2 = pb[2 * NB4];
            float sx = s0.x + s1.x + s2.x;
            float sy = s0.y + s1.y + s2.y;
            float sz = s0.z + s1.z + s2.z;
            float sw = s0.w + s1.w + s2.w;
            acc0[b] += sx * wa.x + sy * wa.z + sz * wb.x + sw * wb.z;
            acc1[b] += sx * wa.y + sy * wa.w + sz * wb.y + sw * wb.w;
        }
    }

#pragma unroll
    for (int b = 0; b < BATCH; ++b) {
#pragma unroll
        for (int off = 32; off > 0; off >>= 1) {
            acc0[b] += __shfl_down(acc0[b], off, 64);
            acc1[b] += __shfl_down(acc1[b], off, 64);
        }
    }

    __shared__ float sred[4][16];
    int lane = threadIdx.x & 63;
    int wave = threadIdx.x >> 6;
    if (lane == 0) {
#pragma unroll
        for (int b = 0; b < BATCH; ++b) {
            sred[wave][2 * b + 0] = acc0[b];
            sred[wave][2 * b + 1] = acc1[b];
        }
    }
    __syncthreads();
    if (threadIdx.x < 16) {
        float s = sred[0][threadIdx.x] + sred[1][threadIdx.x] +
                  sred[2][threadIdx.x] + sred[3][threadIdx.x];
        atomicAdd(&out[threadIdx.x], s);
    }
}

// ---- fallback (round-1 unsorted path) if ws is too small ----
__global__ void zero_out_kernel(float* __restrict__ out) {
    int i = threadIdx.x;
    if (i < 16) out[i] = 0.0f;
}

__global__ __launch_bounds__(256) void interp_grad_kernel(
    const float* __restrict__ imgs, const float* __restrict__ z,
    float* __restrict__ out, int npts)
{
    int p = blockIdx.x * blockDim.x + threadIdx.x;
    float acc0[BATCH];
    float acc1[BATCH];
#pragma unroll
    for (int b = 0; b < BATCH; ++b) { acc0[b] = 0.0f; acc1[b] = 0.0f; }
    if (p < npts) {
        float2 zz = ((const float2*)z)[p];
        float x0y = zz.x * (float)(NYX - 1);
        float x0x = zz.y * (float)(NYX - 1);
        bool oob = (x0y < 0.0f) || (x0y > (float)(NYX - 1)) ||
                   (x0x < 0.0f) || (x0x > (float)(NYX - 1));
        if (!oob) {
            int yg = min((int)floorf(x0y), NYX - 2);
            int xg = min((int)floorf(x0x), NYX - 2);
            float fy = (float)yg - x0y;
            float fx = (float)xg - x0x;
            const float* base = imgs + (size_t)yg * NYX + xg;
#pragma unroll
            for (int b = 0; b < BATCH; ++b) {
#pragma unroll
                for (int c = 0; c < CH; ++c) {
                    const float* pl = base + (size_t)(b * CH + c) * (size_t)NPIX;
                    float g00 = pl[0];
                    float g01 = pl[1];
                    float g10 = pl[NYX];
                    float g11 = pl[NYX + 1];
                    float a1 = g10 - g00;
                    float a2 = g11 - g01;
                    float a3 = g01 - g00;
                    float d  = a1 - a2;
                    acc0[b] += d * fx + a1;
                    acc1[b] += d * fy + a3;
                }
            }
        }
    }
#pragma unroll
    for (int b = 0; b < BATCH; ++b) {
#pragma unroll
        for (int off = 32; off > 0; off >>= 1) {
            acc0[b] += __shfl_down(acc0[b], off, 64);
            acc1[b] += __shfl_down(acc1[b], off, 64);
        }
    }
    __shared__ float sred[4][16];
    int lane = threadIdx.x & 63;
    int wave = threadIdx.x >> 6;
    if (lane == 0) {
#pragma unroll
        for (int b = 0; b < BATCH; ++b) {
            sred[wave][2 * b + 0] = acc0[b];
            sred[wave][2 * b + 1] = acc1[b];
        }
    }
    __syncthreads();
    if (threadIdx.x < 16) {
        float s = sred[0][threadIdx.x] + sred[1][threadIdx.x] +
                  sred[2][threadIdx.x] + sred[3][threadIdx.x];
        atomicAdd(&out[threadIdx.x], s);
    }
}

extern "C" void kernel_launch(void* const* d_in, const int* in_sizes, int n_in,
                              void* d_out, int out_size, void* d_ws, size_t ws_size,
                              hipStream_t stream) {
    const float* imgs = (const float*)d_in[0];
    const float* z    = (const float*)d_in[1];
    float* out        = (float*)d_out;
    int npts = in_sizes[1] / 2;

    size_t ws_need = (size_t)NPIX * sizeof(float2);   // 8 MB
    int blocks = (npts + 255) / 256;

    if (ws_size < ws_need) {
        zero_out_kernel<<<1, 64, 0, stream>>>(out);
        interp_grad_kernel<<<blocks, 256, 0, stream>>>(imgs, z, out, npts);
        return;
    }

    float2* W  = (float2*)d_ws;
    float4* W4 = (float4*)d_ws;

    zero_w_kernel<<<(NPIX / 2 + 255) / 256, 256, 0, stream>>>(W4, out);
    scatter_w_kernel<<<blocks, 256, 0, stream>>>(z, W, npts);
    dot_kernel<<<512, 256, 0, stream>>>((const float4*)imgs, W4, out);
}

// Round 7
// 213.094 us; speedup vs baseline: 2.5736x; 2.5736x over previous
//
#include <hip/hip_runtime.h>

// imgs (8,3,1024,1024) fp32, z (1e6,2) fp32 -> out (8,2) fp32.
// R7: linear-in-imgs reformulation with ONE u64 atomic per point.
//   gc0 = Dy[yg][xg] + u*M[yg][xg],  gc1 = Dx[yg][xg] + v*M[yg][xg]
// where S_b = sum_c imgs[b,c], Dy = d/dy S, Dx = d/dx S, M = mixed 2nd diff.
// Per-pixel stats N = count, U = sum u, V = sum v packed in u64 (V:22|U:22|N:20,
// fixed-point 2^16). Then out0[b] = sum_p N*Dy + U*M, out1[b] = sum_p N*Dx + V*M,
// evaluated by summation-by-parts so imgs is read exactly once, coalesced:
//   c0[y][x] = N[y-1][x]-N[y][x] + U[y-1][x-1]-U[y-1][x]-U[y][x-1]+U[y][x]
//   c1[y][x] = N[y][x-1]-N[y][x] + V[y-1][x-1]-V[y-1][x]-V[y][x-1]+V[y][x]
//   out[b][j] = sum_pix S_b * cj   (c0,c1 b-independent)
// R6 lesson: random-line atomics cost ~50ns/transaction device-wide (8M -> 395us);
// this cuts 8M transactions -> 1M.

#define NYX 1024
#define NPIX (NYX * NYX)
#define NB4 (NPIX / 4)
#define BATCH 8
#define CH 3
#define DOT_BLOCKS (NPIX / 4 / 256)   // 1024 blocks, 1 float4-group/thread

#define FSCALE 65536.0f
#define FINV   (1.0f / 65536.0f)
#define FMASK  0x3FFFFFu

// ws layout: u64 X[NPIX] (8 MB) at 0; float partials[DOT_BLOCKS*16] at 8 MB.
#define WS_PART (NPIX * 8)

__global__ __launch_bounds__(256) void zero_x_kernel(ulonglong2* __restrict__ X2)
{
    int t = blockIdx.x * blockDim.x + threadIdx.x;
    if (t < NPIX / 2) X2[t] = make_ulonglong2(0ULL, 0ULL);
}

__global__ __launch_bounds__(256) void scatter_x_kernel(
    const float* __restrict__ z, unsigned long long* __restrict__ X, int npts)
{
    int p = blockIdx.x * blockDim.x + threadIdx.x;
    if (p >= npts) return;
    float2 zz = ((const float2*)z)[p];
    float x0y = zz.x * (float)(NYX - 1);
    float x0x = zz.y * (float)(NYX - 1);
    bool oob = (x0y < 0.0f) || (x0y > (float)(NYX - 1)) ||
               (x0x < 0.0f) || (x0x > (float)(NYX - 1));
    if (oob) return;
    int yg = min((int)floorf(x0y), NYX - 2);
    int xg = min((int)floorf(x0x), NYX - 2);
    float u = x0x - (float)xg;   // [0,1)
    float v = x0y - (float)yg;
    unsigned long long qU = (unsigned long long)(unsigned)(u * FSCALE + 0.5f);
    unsigned long long qV = (unsigned long long)(unsigned)(v * FSCALE + 0.5f);
    unsigned long long val = qV | (qU << 22) | (1ULL << 44);
    atomicAdd(&X[yg * NYX + xg], val);
}

__device__ __forceinline__ float dN(unsigned long long w) {
    return (float)(unsigned)(w >> 44);
}
__device__ __forceinline__ float dU(unsigned long long w) {
    return (float)((unsigned)(w >> 22) & FMASK) * FINV;
}
__device__ __forceinline__ float dV(unsigned long long w) {
    return (float)((unsigned)w & FMASK) * FINV;
}

__global__ __launch_bounds__(256) void dot_kernel(
    const float4* __restrict__ imgs4, const unsigned long long* __restrict__ X,
    float* __restrict__ partials)
{
    int g = blockIdx.x * blockDim.x + threadIdx.x;   // float4-group id
    int p0 = g * 4;
    int y = p0 >> 10;
    int x0 = p0 & (NYX - 1);

    // cur[i] = X[y][x0-1+i], up[i] = X[y-1][x0-1+i], i=0..4 (zero-extended)
    unsigned long long cur[5], up[5];
    cur[0] = (x0 > 0) ? X[p0 - 1] : 0ULL;
    cur[1] = X[p0 + 0];
    cur[2] = X[p0 + 1];
    cur[3] = X[p0 + 2];
    cur[4] = X[p0 + 3];
    if (y > 0) {
        int q = p0 - NYX;
        up[0] = (x0 > 0) ? X[q - 1] : 0ULL;
        up[1] = X[q + 0];
        up[2] = X[q + 1];
        up[3] = X[q + 2];
        up[4] = X[q + 3];
    } else {
        up[0] = up[1] = up[2] = up[3] = up[4] = 0ULL;
    }

    float c0[4], c1[4];
#pragma unroll
    for (int i = 0; i < 4; ++i) {
        // pixel x = x0+i: corners (y-1,x-1)=up[i], (y-1,x)=up[i+1],
        //                 (y, x-1)=cur[i], (y, x)=cur[i+1]
        c0[i] = dN(up[i + 1]) - dN(cur[i + 1])
              + dU(up[i]) - dU(up[i + 1]) - dU(cur[i]) + dU(cur[i + 1]);
        c1[i] = dN(cur[i]) - dN(cur[i + 1])
              + dV(up[i]) - dV(up[i + 1]) - dV(cur[i]) + dV(cur[i + 1]);
    }

    float acc0[BATCH];
    float acc1[BATCH];
#pragma unroll
    for (int b = 0; b < BATCH; ++b) {
        const float4* pb = imgs4 + (size_t)(b * CH) * NB4 + g;
        float4 s0 = pb[0];
        float4 s1 = pb[NB4];
        float4 s2 = pb[2 * NB4];
        float sx = s0.x + s1.x + s2.x;
        float sy = s0.y + s1.y + s2.y;
        float sz = s0.z + s1.z + s2.z;
        float sw = s0.w + s1.w + s2.w;
        acc0[b] = sx * c0[0] + sy * c0[1] + sz * c0[2] + sw * c0[3];
        acc1[b] = sx * c1[0] + sy * c1[1] + sz * c1[2] + sw * c1[3];
    }

#pragma unroll
    for (int b = 0; b < BATCH; ++b) {
#pragma unroll
        for (int off = 32; off > 0; off >>= 1) {
            acc0[b] += __shfl_down(acc0[b], off, 64);
            acc1[b] += __shfl_down(acc1[b], off, 64);
        }
    }

    __shared__ float sred[4][16];
    int lane = threadIdx.x & 63;
    int wave = threadIdx.x >> 6;
    if (lane == 0) {
#pragma unroll
        for (int b = 0; b < BATCH; ++b) {
            sred[wave][2 * b + 0] = acc0[b];
            sred[wave][2 * b + 1] = acc1[b];
        }
    }
    __syncthreads();
    if (threadIdx.x < 16) {
        float s = sred[0][threadIdx.x] + sred[1][threadIdx.x] +
                  sred[2][threadIdx.x] + sred[3][threadIdx.x];
        partials[blockIdx.x * 16 + threadIdx.x] = s;
    }
}

__global__ __launch_bounds__(256) void final_reduce_kernel(
    const float* __restrict__ partials, float* __restrict__ out)
{
    // 256 threads: thread = chunk*16 + j; 16 chunks x 64 rows each
    int j = threadIdx.x & 15;
    int chunk = threadIdx.x >> 4;
    float s = 0.0f;
    int r0 = chunk * (DOT_BLOCKS / 16);
    for (int r = r0; r < r0 + (DOT_BLOCKS / 16); ++r)
        s += partials[r * 16 + j];
    __shared__ float tmp[256];
    tmp[threadIdx.x] = s;
    __syncthreads();
    if (threadIdx.x < 16) {
        float t = 0.0f;
#pragma unroll
        for (int c = 0; c < 16; ++c) t += tmp[c * 16 + threadIdx.x];
        out[threadIdx.x] = t;
    }
}

// ---- fallback (round-1 unsorted path) if ws is too small ----
__global__ void zero_out_kernel(float* __restrict__ out) {
    int i = threadIdx.x;
    if (i < 16) out[i] = 0.0f;
}

__global__ __launch_bounds__(256) void interp_grad_kernel(
    const float* __restrict__ imgs, const float* __restrict__ z,
    float* __restrict__ out, int npts)
{
    int p = blockIdx.x * blockDim.x + threadIdx.x;
    float acc0[BATCH];
    float acc1[BATCH];
#pragma unroll
    for (int b = 0; b < BATCH; ++b) { acc0[b] = 0.0f; acc1[b] = 0.0f; }
    if (p < npts) {
        float2 zz = ((const float2*)z)[p];
        float x0y = zz.x * (float)(NYX - 1);
        float x0x = zz.y * (float)(NYX - 1);
        bool oob = (x0y < 0.0f) || (x0y > (float)(NYX - 1)) ||
                   (x0x < 0.0f) || (x0x > (float)(NYX - 1));
        if (!oob) {
            int yg = min((int)floorf(x0y), NYX - 2);
            int xg = min((int)floorf(x0x), NYX - 2);
            float fy = (float)yg - x0y;
            float fx = (float)xg - x0x;
            const float* base = imgs + (size_t)yg * NYX + xg;
#pragma unroll
            for (int b = 0; b < BATCH; ++b) {
#pragma unroll
                for (int c = 0; c < CH; ++c) {
                    const float* pl = base + (size_t)(b * CH + c) * (size_t)NPIX;
                    float g00 = pl[0];
                    float g01 = pl[1];
                    float g10 = pl[NYX];
                    float g11 = pl[NYX + 1];
                    float a1 = g10 - g00;
                    float a2 = g11 - g01;
                    float a3 = g01 - g00;
                    float d  = a1 - a2;
                    acc0[b] += d * fx + a1;
                    acc1[b] += d * fy + a3;
                }
            }
        }
    }
#pragma unroll
    for (int b = 0; b < BATCH; ++b) {
#pragma unroll
        for (int off = 32; off > 0; off >>= 1) {
            acc0[b] += __shfl_down(acc0[b], off, 64);
            acc1[b] += __shfl_down(acc1[b], off, 64);
        }
    }
    __shared__ float sred[4][16];
    int lane = threadIdx.x & 63;
    int wave = threadIdx.x >> 6;
    if (lane == 0) {
#pragma unroll
        for (int b = 0; b < BATCH; ++b) {
            sred[wave][2 * b + 0] = acc0[b];
            sred[wave][2 * b + 1] = acc1[b];
        }
    }
    __syncthreads();
    if (threadIdx.x < 16) {
        float s = sred[0][threadIdx.x] + sred[1][threadIdx.x] +
                  sred[2][threadIdx.x] + sred[3][threadIdx.x];
        atomicAdd(&out[threadIdx.x], s);
    }
}

extern "C" void kernel_launch(void* const* d_in, const int* in_sizes, int n_in,
                              void* d_out, int out_size, void* d_ws, size_t ws_size,
                              hipStream_t stream) {
    const float* imgs = (const float*)d_in[0];
    const float* z    = (const float*)d_in[1];
    float* out        = (float*)d_out;
    int npts = in_sizes[1] / 2;

    size_t ws_need = (size_t)WS_PART + (size_t)DOT_BLOCKS * 16 * sizeof(float);
    int blocks = (npts + 255) / 256;

    if (ws_size < ws_need) {
        zero_out_kernel<<<1, 64, 0, stream>>>(out);
        interp_grad_kernel<<<blocks, 256, 0, stream>>>(imgs, z, out, npts);
        return;
    }

    unsigned long long* X = (unsigned long long*)d_ws;
    float* partials = (float*)((char*)d_ws + WS_PART);

    zero_x_kernel<<<(NPIX / 2 + 255) / 256, 256, 0, stream>>>((ulonglong2*)d_ws);
    scatter_x_kernel<<<blocks, 256, 0, stream>>>(z, X, npts);
    dot_kernel<<<DOT_BLOCKS, 256, 0, stream>>>((const float4*)imgs, X, partials);
    final_reduce_kernel<<<1, 256, 0, stream>>>(partials, out);
}